// Round 1
// baseline (314.328 us; speedup 1.0000x reference)
//
#include <hip/hip_runtime.h>

// ---------------------------------------------------------------------------
// CriticWithGNN: only nodes < n_agents reach the output, so only edges with
// receiver < n_agents (~2% of E) need the message MLP. FLOPs: 210G -> ~5G.
// ---------------------------------------------------------------------------

#define STRIDE 260   // LDS row stride in words (mult of 4 for float4, 260%32=4)

__global__ void zero_ws(float* ws, int nwords) {
    int i = blockIdx.x * blockDim.x + threadIdx.x;
    if (i < nwords) ws[i] = 0.f;
}

// Compact edges with receiver < n_agents. LDS-staged so each block does ONE
// global atomicAdd (avoids thousands of serialized same-address atomics).
#define FILT_CHUNK 4096
__global__ void filter_edges(const int* __restrict__ senders,
                             const int* __restrict__ receivers,
                             int E, int n_agents, int cap,
                             int* __restrict__ counter, int2* __restrict__ edges) {
    __shared__ int lcount;
    __shared__ int lbase;
    __shared__ int2 lbuf[FILT_CHUNK];
    if (threadIdx.x == 0) lcount = 0;
    __syncthreads();
    int start = blockIdx.x * FILT_CHUNK;
    int end = min(start + FILT_CHUNK, E);
    for (int idx = start + (int)threadIdx.x; idx < end; idx += 256) {
        int r = receivers[idx];
        if (r < n_agents) {
            int p = atomicAdd(&lcount, 1);
            lbuf[p] = make_int2(senders[idx], r);
        }
    }
    __syncthreads();
    if (threadIdx.x == 0) lbase = atomicAdd(counter, lcount);
    __syncthreads();
    for (int i = (int)threadIdx.x; i < lcount; i += 256) {
        int pos = lbase + i;
        if (pos < cap) edges[pos] = lbuf[i];
    }
}

// Generic dense layer on an LDS tile: out[TE][NOUT] = act(in[TE][NIN] @ W + b)
// 256 threads; each thread computes 4 consecutive out-cols for ER edge rows.
// LDS in-reads are wave-broadcast (all lanes of a wave share ty -> same addr).
template<int TE, int NIN, int NOUT, bool RELU, int OOFF>
__device__ __forceinline__ void mlp_layer(const float* in_lds, float* out_lds,
                                          const float* __restrict__ W,
                                          const float* __restrict__ b) {
    constexpr int TX = NOUT / 4;
    constexpr int TY = 256 / TX;
    static_assert(TE % TY == 0, "tile rows must divide");
    constexpr int ER = TE / TY;
    const int t = (int)threadIdx.x;
    const int tx = t % TX;
    const int ty = t / TX;
    const int o  = tx * 4;
    const int e0 = ty * ER;
    float acc[ER][4];
#pragma unroll
    for (int er = 0; er < ER; ++er) {
        acc[er][0] = 0.f; acc[er][1] = 0.f; acc[er][2] = 0.f; acc[er][3] = 0.f;
    }
#pragma unroll 2
    for (int k = 0; k < NIN; k += 4) {
        float4 w0 = *(const float4*)(W + (size_t)(k + 0) * NOUT + o);
        float4 w1 = *(const float4*)(W + (size_t)(k + 1) * NOUT + o);
        float4 w2 = *(const float4*)(W + (size_t)(k + 2) * NOUT + o);
        float4 w3 = *(const float4*)(W + (size_t)(k + 3) * NOUT + o);
#pragma unroll
        for (int er = 0; er < ER; ++er) {
            float4 a = *(const float4*)(in_lds + (e0 + er) * STRIDE + k);
            acc[er][0] += a.x * w0.x + a.y * w1.x + a.z * w2.x + a.w * w3.x;
            acc[er][1] += a.x * w0.y + a.y * w1.y + a.z * w2.y + a.w * w3.y;
            acc[er][2] += a.x * w0.z + a.y * w1.z + a.z * w2.z + a.w * w3.z;
            acc[er][3] += a.x * w0.w + a.y * w1.w + a.z * w2.w + a.w * w3.w;
        }
    }
    const float4 bias = *(const float4*)(b + o);
#pragma unroll
    for (int er = 0; er < ER; ++er) {
        float4 v;
        v.x = acc[er][0] + bias.x; v.y = acc[er][1] + bias.y;
        v.z = acc[er][2] + bias.z; v.w = acc[er][3] + bias.w;
        if (RELU) {
            v.x = fmaxf(v.x, 0.f); v.y = fmaxf(v.y, 0.f);
            v.z = fmaxf(v.z, 0.f); v.w = fmaxf(v.w, 0.f);
        }
        *(float4*)(out_lds + (e0 + er) * STRIDE + OOFF + o) = v;
    }
}

// Message MLP over compacted edges + atomic scatter into aggr[n_agents][128].
// 32 edges per tile, grid-stride over tiles (count only known on device).
__global__ __launch_bounds__(256, 2)
void edge_mlp(const float* __restrict__ x, const int2* __restrict__ edges,
              const int* __restrict__ counter, int cap, float* __restrict__ aggr,
              const float* __restrict__ Wm1, const float* __restrict__ bm1,
              const float* __restrict__ Wm2, const float* __restrict__ bm2,
              const float* __restrict__ Wm3, const float* __restrict__ bm3) {
    __shared__ float bufA[32 * STRIDE];
    __shared__ float bufB[32 * STRIDE];
    __shared__ int sL[32], rL[32];
    const int count = min(counter[0], cap);
    const int ntiles = (count + 31) >> 5;
    const int t = (int)threadIdx.x;
    for (int tile = (int)blockIdx.x; tile < ntiles; tile += (int)gridDim.x) {
        const int base = tile * 32;
        if (t < 32) {
            int eg = base + t;
            int2 ed = (eg < count) ? edges[eg] : make_int2(0, -1);
            sL[t] = ed.x; rL[t] = ed.y;
        }
        __syncthreads();
        // gather h0 = [x[sender] | x[receiver]]  -> bufA[32][128]
        for (int idx = t; idx < 32 * 128; idx += 256) {
            int e = idx >> 7, f = idx & 127;
            int node = (f < 64) ? sL[e] : rL[e];
            float v = 0.f;
            if (rL[e] >= 0) v = x[(size_t)node * 64 + (f & 63)];
            bufA[e * STRIDE + f] = v;
        }
        __syncthreads();
        mlp_layer<32, 128, 256, true, 0>(bufA, bufB, Wm1, bm1);
        __syncthreads();
        mlp_layer<32, 256, 256, true, 0>(bufB, bufA, Wm2, bm2);
        __syncthreads();
        mlp_layer<32, 256, 128, false, 0>(bufA, bufB, Wm3, bm3);
        __syncthreads();
        // scatter-add msg into aggr (device-scope fp32 atomics)
        for (int idx = t; idx < 32 * 128; idx += 256) {
            int e = idx >> 7, o = idx & 127;
            if (base + e < count) {
                atomicAdd(&aggr[(size_t)rL[e] * 128 + o], bufB[e * STRIDE + o]);
            }
        }
        __syncthreads();
    }
}

// Fused per-node pipeline for the first n_agents nodes:
// aggr -> aggMLP -> concat(x, a) -> updateMLP -> feats; actions -> proj;
// concat(feats, ap) -> headMLP -> q.  8 nodes per 256-thread block.
__global__ __launch_bounds__(256, 2)
void node_update(const float* __restrict__ x, const float* __restrict__ actions,
                 const float* __restrict__ aggr, int n_agents,
                 const float* __restrict__ Wa1, const float* __restrict__ ba1,
                 const float* __restrict__ Wa2, const float* __restrict__ ba2,
                 const float* __restrict__ Wa3, const float* __restrict__ ba3,
                 const float* __restrict__ Wu1, const float* __restrict__ bu1,
                 const float* __restrict__ Wu2, const float* __restrict__ bu2,
                 const float* __restrict__ Wu3, const float* __restrict__ bu3,
                 const float* __restrict__ Wact, const float* __restrict__ bact,
                 const float* __restrict__ Wh1, const float* __restrict__ bh1,
                 const float* __restrict__ Wh2, const float* __restrict__ bh2,
                 const float* __restrict__ Wq,  const float* __restrict__ bq,
                 float* __restrict__ out) {
    __shared__ float bufA[8 * STRIDE];
    __shared__ float bufB[8 * STRIDE];
    const int t = (int)threadIdx.x;
    const int base = (int)blockIdx.x * 8;

    // load aggr rows -> bufA[8][128]
    for (int idx = t; idx < 8 * 128; idx += 256) {
        int e = idx >> 7, k = idx & 127;
        int node = base + e;
        bufA[e * STRIDE + k] = (node < n_agents) ? aggr[(size_t)node * 128 + k] : 0.f;
    }
    __syncthreads();
    mlp_layer<8, 128, 128, true,  0>(bufA, bufB, Wa1, ba1); __syncthreads();
    mlp_layer<8, 128, 128, true,  0>(bufB, bufA, Wa2, ba2); __syncthreads();
    mlp_layer<8, 128, 128, false, 0>(bufA, bufB, Wa3, ba3); __syncthreads();
    // u0 = [x(64) | a(128)] -> bufA width 192
    for (int idx = t; idx < 8 * 64; idx += 256) {
        int e = idx >> 6, f = idx & 63;
        int node = base + e;
        bufA[e * STRIDE + f] = (node < n_agents) ? x[(size_t)node * 64 + f] : 0.f;
    }
    for (int idx = t; idx < 8 * 128; idx += 256) {
        int e = idx >> 7, c = idx & 127;
        bufA[e * STRIDE + 64 + c] = bufB[e * STRIDE + c];
    }
    __syncthreads();
    mlp_layer<8, 192, 256, true,  0>(bufA, bufB, Wu1, bu1); __syncthreads();
    mlp_layer<8, 256, 256, true,  0>(bufB, bufA, Wu2, bu2); __syncthreads();
    mlp_layer<8, 256, 128, false, 0>(bufA, bufB, Wu3, bu3); __syncthreads();
    // feats now in bufB[:, 0:128]. Stage actions -> bufA[:, 0:16]
    for (int idx = t; idx < 8 * 16; idx += 256) {
        int e = idx >> 4, k = idx & 15;
        int node = base + e;
        bufA[e * STRIDE + k] = (node < n_agents) ? actions[(size_t)node * 16 + k] : 0.f;
    }
    __syncthreads();
    // ap = relu(actions @ Wact) written into bufB[:, 128:256] => z in bufB
    mlp_layer<8, 16, 128, true, 128>(bufA, bufB, Wact, bact); __syncthreads();
    mlp_layer<8, 256, 256, true, 0>(bufB, bufA, Wh1, bh1); __syncthreads();
    mlp_layer<8, 256, 256, true, 0>(bufA, bufB, Wh2, bh2); __syncthreads();
    // q = z2 @ Wq + bq  (one thread per node; stride 260 -> conflict-free)
    if (t < 8) {
        int node = base + t;
        if (node < n_agents) {
            float acc = 0.f;
#pragma unroll 4
            for (int k = 0; k < 256; k += 4) {
                float4 z = *(const float4*)(bufB + t * STRIDE + k);
                float4 w = *(const float4*)(Wq + k);
                acc += z.x * w.x + z.y * w.y + z.z * w.z + z.w * w.w;
            }
            out[node] = acc + bq[0];
        }
    }
}

extern "C" void kernel_launch(void* const* d_in, const int* in_sizes, int n_in,
                              void* d_out, int out_size, void* d_ws, size_t ws_size,
                              hipStream_t stream) {
    const float* x        = (const float*)d_in[0];
    const float* actions  = (const float*)d_in[1];
    const int*   senders  = (const int*)d_in[2];
    const int*   receivers= (const int*)d_in[3];
    // d_in[4] = n_agents (device scalar); host-side value == out_size
    const float* Wm1 = (const float*)d_in[5],  *bm1 = (const float*)d_in[6];
    const float* Wm2 = (const float*)d_in[7],  *bm2 = (const float*)d_in[8];
    const float* Wm3 = (const float*)d_in[9],  *bm3 = (const float*)d_in[10];
    const float* Wa1 = (const float*)d_in[11], *ba1 = (const float*)d_in[12];
    const float* Wa2 = (const float*)d_in[13], *ba2 = (const float*)d_in[14];
    const float* Wa3 = (const float*)d_in[15], *ba3 = (const float*)d_in[16];
    const float* Wu1 = (const float*)d_in[17], *bu1 = (const float*)d_in[18];
    const float* Wu2 = (const float*)d_in[19], *bu2 = (const float*)d_in[20];
    const float* Wu3 = (const float*)d_in[21], *bu3 = (const float*)d_in[22];
    const float* Wact= (const float*)d_in[23], *bact= (const float*)d_in[24];
    const float* Wh1 = (const float*)d_in[25], *bh1 = (const float*)d_in[26];
    const float* Wh2 = (const float*)d_in[27], *bh2 = (const float*)d_in[28];
    const float* Wq  = (const float*)d_in[29], *bq  = (const float*)d_in[30];

    const int E = in_sizes[2];
    const int n_agents = out_size;   // q has one entry per agent

    // workspace layout: [0..4) counter | [1024 ..) aggr | [edgeOff ..) edges
    char* ws = (char*)d_ws;
    int*   counter = (int*)ws;
    float* aggr    = (float*)(ws + 1024);
    size_t aggrBytes = (size_t)n_agents * 128 * sizeof(float);
    size_t edgeOff = 1024 + ((aggrBytes + 1023) / 1024) * 1024;
    int2*  edges   = (int2*)(ws + edgeOff);
    int cap = (int)((ws_size > edgeOff) ? (ws_size - edgeOff) / sizeof(int2) : 0);
    if (cap > E) cap = E;

    int zwords = (int)(edgeOff / 4);
    zero_ws<<<(zwords + 255) / 256, 256, 0, stream>>>((float*)ws, zwords);

    int fblocks = (E + FILT_CHUNK - 1) / FILT_CHUNK;
    filter_edges<<<fblocks, 256, 0, stream>>>(senders, receivers, E, n_agents,
                                              cap, counter, edges);

    edge_mlp<<<768, 256, 0, stream>>>(x, edges, counter, cap, aggr,
                                      Wm1, bm1, Wm2, bm2, Wm3, bm3);

    node_update<<<(n_agents + 7) / 8, 256, 0, stream>>>(
        x, actions, aggr, n_agents,
        Wa1, ba1, Wa2, ba2, Wa3, ba3,
        Wu1, bu1, Wu2, bu2, Wu3, bu3,
        Wact, bact, Wh1, bh1, Wh2, bh2, Wq, bq,
        (float*)d_out);
}

// Round 2
// 299.487 us; speedup vs baseline: 1.0496x; 1.0496x over previous
//
#include <hip/hip_runtime.h>

// ---------------------------------------------------------------------------
// CriticWithGNN: only nodes < n_agents reach the output, so only edges with
// receiver < n_agents (~2% of E) need the message MLP. FLOPs: 210G -> ~5G.
// R2: 16-edge tiles (4 blocks/CU), 4-node update blocks (256 blocks).
// ---------------------------------------------------------------------------

#define STRIDE 260   // LDS row stride in words (mult of 4 for float4, 260%32=4)

// Compact edges with receiver < n_agents. LDS-staged so each block does ONE
// global atomicAdd (avoids thousands of serialized same-address atomics).
#define FILT_CHUNK 4096
__global__ void filter_edges(const int* __restrict__ senders,
                             const int* __restrict__ receivers,
                             int E, int n_agents, int cap,
                             int* __restrict__ counter, int2* __restrict__ edges) {
    __shared__ int lcount;
    __shared__ int lbase;
    __shared__ int2 lbuf[FILT_CHUNK];
    if (threadIdx.x == 0) lcount = 0;
    __syncthreads();
    int start = blockIdx.x * FILT_CHUNK;
    int end = min(start + FILT_CHUNK, E);
    for (int idx = start + (int)threadIdx.x; idx < end; idx += 256) {
        int r = receivers[idx];
        if (r < n_agents) {
            int p = atomicAdd(&lcount, 1);
            lbuf[p] = make_int2(senders[idx], r);
        }
    }
    __syncthreads();
    if (threadIdx.x == 0) lbase = atomicAdd(counter, lcount);
    __syncthreads();
    for (int i = (int)threadIdx.x; i < lcount; i += 256) {
        int pos = lbase + i;
        if (pos < cap) edges[pos] = lbuf[i];
    }
}

// Generic dense layer on an LDS tile: out[TE][NOUT] = act(in[TE][NIN] @ W + b)
// 256 threads; each thread computes COLS consecutive out-cols for ER rows.
// LDS in-reads are wave-broadcast (lanes of a wave share ty -> same address).
template<int TE, int NIN, int NOUT, int COLS, bool RELU, int OOFF>
__device__ __forceinline__ void mlp_layer(const float* in_lds, float* out_lds,
                                          const float* __restrict__ W,
                                          const float* __restrict__ b) {
    constexpr int TX = NOUT / COLS;
    constexpr int TY = 256 / TX;
    static_assert(TE % TY == 0, "tile rows must divide");
    constexpr int ER = TE / TY;
    const int t = (int)threadIdx.x;
    const int tx = t % TX;
    const int ty = t / TX;
    const int o  = tx * COLS;
    const int e0 = ty * ER;
    float acc[ER][COLS];
#pragma unroll
    for (int er = 0; er < ER; ++er)
#pragma unroll
        for (int c = 0; c < COLS; ++c) acc[er][c] = 0.f;

#pragma unroll 2
    for (int k = 0; k < NIN; k += 4) {
        float w[4][COLS];
#pragma unroll
        for (int j = 0; j < 4; ++j) {
            if (COLS == 4) {
                float4 wv = *(const float4*)(W + (size_t)(k + j) * NOUT + o);
                w[j][0] = wv.x; w[j][1] = wv.y; w[j][2] = wv.z; w[j][3] = wv.w;
            } else {
                float2 wv = *(const float2*)(W + (size_t)(k + j) * NOUT + o);
                w[j][0] = wv.x; w[j][1] = wv.y;
            }
        }
#pragma unroll
        for (int er = 0; er < ER; ++er) {
            float4 a = *(const float4*)(in_lds + (e0 + er) * STRIDE + k);
#pragma unroll
            for (int c = 0; c < COLS; ++c) {
                acc[er][c] += a.x * w[0][c] + a.y * w[1][c]
                            + a.z * w[2][c] + a.w * w[3][c];
            }
        }
    }
#pragma unroll
    for (int er = 0; er < ER; ++er) {
        float v[COLS];
#pragma unroll
        for (int c = 0; c < COLS; ++c) {
            v[c] = acc[er][c] + b[o + c];
            if (RELU) v[c] = fmaxf(v[c], 0.f);
        }
        float* dst = out_lds + (e0 + er) * STRIDE + OOFF + o;
        if (COLS == 4) *(float4*)dst = make_float4(v[0], v[1], v[2], v[3]);
        else           *(float2*)dst = make_float2(v[0], v[1]);
    }
}

// Message MLP over compacted edges + atomic scatter into aggr[n_agents][128].
// 16 edges per tile, grid-stride over tiles (count only known on device).
#define ETE 16
__global__ __launch_bounds__(256, 4)
void edge_mlp(const float* __restrict__ x, const int2* __restrict__ edges,
              const int* __restrict__ counter, int cap, float* __restrict__ aggr,
              const float* __restrict__ Wm1, const float* __restrict__ bm1,
              const float* __restrict__ Wm2, const float* __restrict__ bm2,
              const float* __restrict__ Wm3, const float* __restrict__ bm3) {
    __shared__ float bufA[ETE * STRIDE];
    __shared__ float bufB[ETE * STRIDE];
    __shared__ int sL[ETE], rL[ETE];
    const int count = min(counter[0], cap);
    const int ntiles = (count + ETE - 1) / ETE;
    const int t = (int)threadIdx.x;
    for (int tile = (int)blockIdx.x; tile < ntiles; tile += (int)gridDim.x) {
        const int base = tile * ETE;
        if (t < ETE) {
            int eg = base + t;
            int2 ed = (eg < count) ? edges[eg] : make_int2(0, -1);
            sL[t] = ed.x; rL[t] = ed.y;
        }
        __syncthreads();
        // gather h0 = [x[sender] | x[receiver]] -> bufA[16][128], float4 loads
        {
            int slots = ETE * 128 / 4;              // 512 float4 slots
            for (int idx = t; idx < slots; idx += 256) {
                int e = idx >> 5;                   // 32 float4 per row
                int f4 = (idx & 31) * 4;
                int node = (f4 < 64) ? sL[e] : rL[e];
                float4 v = make_float4(0.f, 0.f, 0.f, 0.f);
                if (rL[e] >= 0) v = *(const float4*)(x + (size_t)node * 64 + (f4 & 63));
                *(float4*)(bufA + e * STRIDE + f4) = v;
            }
        }
        __syncthreads();
        mlp_layer<ETE, 128, 256, 4, true,  0>(bufA, bufB, Wm1, bm1);
        __syncthreads();
        mlp_layer<ETE, 256, 256, 4, true,  0>(bufB, bufA, Wm2, bm2);
        __syncthreads();
        mlp_layer<ETE, 256, 128, 4, false, 0>(bufA, bufB, Wm3, bm3);
        __syncthreads();
        // scatter-add msg into aggr (device-scope fp32 atomics)
        for (int idx = t; idx < ETE * 128; idx += 256) {
            int e = idx >> 7, o = idx & 127;
            if (base + e < count) {
                atomicAdd(&aggr[(size_t)rL[e] * 128 + o], bufB[e * STRIDE + o]);
            }
        }
        __syncthreads();
    }
}

// Fused per-node pipeline for the first n_agents nodes:
// aggr -> aggMLP -> concat(x, a) -> updateMLP -> feats; actions -> proj;
// concat(feats, ap) -> headMLP -> q.  4 nodes per 256-thread block.
#define NTE 4
__global__ __launch_bounds__(256, 2)
void node_update(const float* __restrict__ x, const float* __restrict__ actions,
                 const float* __restrict__ aggr, int n_agents,
                 const float* __restrict__ Wa1, const float* __restrict__ ba1,
                 const float* __restrict__ Wa2, const float* __restrict__ ba2,
                 const float* __restrict__ Wa3, const float* __restrict__ ba3,
                 const float* __restrict__ Wu1, const float* __restrict__ bu1,
                 const float* __restrict__ Wu2, const float* __restrict__ bu2,
                 const float* __restrict__ Wu3, const float* __restrict__ bu3,
                 const float* __restrict__ Wact, const float* __restrict__ bact,
                 const float* __restrict__ Wh1, const float* __restrict__ bh1,
                 const float* __restrict__ Wh2, const float* __restrict__ bh2,
                 const float* __restrict__ Wq,  const float* __restrict__ bq,
                 float* __restrict__ out) {
    __shared__ float bufA[NTE * STRIDE];
    __shared__ float bufB[NTE * STRIDE];
    const int t = (int)threadIdx.x;
    const int base = (int)blockIdx.x * NTE;

    // load aggr rows -> bufA[4][128] (float4)
    if (t < NTE * 128 / 4) {
        int e = t >> 5, f4 = (t & 31) * 4;
        int node = base + e;
        float4 v = make_float4(0.f, 0.f, 0.f, 0.f);
        if (node < n_agents) v = *(const float4*)(aggr + (size_t)node * 128 + f4);
        *(float4*)(bufA + e * STRIDE + f4) = v;
    }
    __syncthreads();
    mlp_layer<NTE, 128, 128, 2, true,  0>(bufA, bufB, Wa1, ba1); __syncthreads();
    mlp_layer<NTE, 128, 128, 2, true,  0>(bufB, bufA, Wa2, ba2); __syncthreads();
    mlp_layer<NTE, 128, 128, 2, false, 0>(bufA, bufB, Wa3, ba3); __syncthreads();
    // u0 = [x(64) | a(128)] -> bufA width 192
    if (t < NTE * 64 / 4) {
        int e = t >> 4, f4 = (t & 15) * 4;
        int node = base + e;
        float4 v = make_float4(0.f, 0.f, 0.f, 0.f);
        if (node < n_agents) v = *(const float4*)(x + (size_t)node * 64 + f4);
        *(float4*)(bufA + e * STRIDE + f4) = v;
    }
    if (t < NTE * 128 / 4) {
        int e = t >> 5, f4 = (t & 31) * 4;
        *(float4*)(bufA + e * STRIDE + 64 + f4) = *(const float4*)(bufB + e * STRIDE + f4);
    }
    __syncthreads();
    mlp_layer<NTE, 192, 256, 4, true,  0>(bufA, bufB, Wu1, bu1); __syncthreads();
    mlp_layer<NTE, 256, 256, 4, true,  0>(bufB, bufA, Wu2, bu2); __syncthreads();
    mlp_layer<NTE, 256, 128, 2, false, 0>(bufA, bufB, Wu3, bu3); __syncthreads();
    // feats now in bufB[:, 0:128]. Stage actions -> bufA[:, 0:16]
    if (t < NTE * 16 / 4) {
        int e = t >> 2, f4 = (t & 3) * 4;
        int node = base + e;
        float4 v = make_float4(0.f, 0.f, 0.f, 0.f);
        if (node < n_agents) v = *(const float4*)(actions + (size_t)node * 16 + f4);
        *(float4*)(bufA + e * STRIDE + f4) = v;
    }
    __syncthreads();
    // ap = relu(actions @ Wact) written into bufB[:, 128:256] => z in bufB
    mlp_layer<NTE, 16, 128, 2, true, 128>(bufA, bufB, Wact, bact); __syncthreads();
    mlp_layer<NTE, 256, 256, 4, true, 0>(bufB, bufA, Wh1, bh1); __syncthreads();
    mlp_layer<NTE, 256, 256, 4, true, 0>(bufA, bufB, Wh2, bh2); __syncthreads();
    // q = z2 @ Wq + bq  (one thread per node; stride 260 -> conflict-free)
    if (t < NTE) {
        int node = base + t;
        if (node < n_agents) {
            float acc = 0.f;
#pragma unroll 4
            for (int k = 0; k < 256; k += 4) {
                float4 z = *(const float4*)(bufB + t * STRIDE + k);
                float4 w = *(const float4*)(Wq + k);
                acc += z.x * w.x + z.y * w.y + z.z * w.z + z.w * w.w;
            }
            out[node] = acc + bq[0];
        }
    }
}

extern "C" void kernel_launch(void* const* d_in, const int* in_sizes, int n_in,
                              void* d_out, int out_size, void* d_ws, size_t ws_size,
                              hipStream_t stream) {
    const float* x        = (const float*)d_in[0];
    const float* actions  = (const float*)d_in[1];
    const int*   senders  = (const int*)d_in[2];
    const int*   receivers= (const int*)d_in[3];
    // d_in[4] = n_agents (device scalar); host-side value == out_size
    const float* Wm1 = (const float*)d_in[5],  *bm1 = (const float*)d_in[6];
    const float* Wm2 = (const float*)d_in[7],  *bm2 = (const float*)d_in[8];
    const float* Wm3 = (const float*)d_in[9],  *bm3 = (const float*)d_in[10];
    const float* Wa1 = (const float*)d_in[11], *ba1 = (const float*)d_in[12];
    const float* Wa2 = (const float*)d_in[13], *ba2 = (const float*)d_in[14];
    const float* Wa3 = (const float*)d_in[15], *ba3 = (const float*)d_in[16];
    const float* Wu1 = (const float*)d_in[17], *bu1 = (const float*)d_in[18];
    const float* Wu2 = (const float*)d_in[19], *bu2 = (const float*)d_in[20];
    const float* Wu3 = (const float*)d_in[21], *bu3 = (const float*)d_in[22];
    const float* Wact= (const float*)d_in[23], *bact= (const float*)d_in[24];
    const float* Wh1 = (const float*)d_in[25], *bh1 = (const float*)d_in[26];
    const float* Wh2 = (const float*)d_in[27], *bh2 = (const float*)d_in[28];
    const float* Wq  = (const float*)d_in[29], *bq  = (const float*)d_in[30];

    const int E = in_sizes[2];
    const int n_agents = out_size;   // q has one entry per agent

    // workspace layout: [0..4) counter | [1024 ..) aggr | [edgeOff ..) edges
    char* ws = (char*)d_ws;
    int*   counter = (int*)ws;
    float* aggr    = (float*)(ws + 1024);
    size_t aggrBytes = (size_t)n_agents * 128 * sizeof(float);
    size_t edgeOff = 1024 + ((aggrBytes + 1023) / 1024) * 1024;
    int2*  edges   = (int2*)(ws + edgeOff);
    int cap = (int)((ws_size > edgeOff) ? (ws_size - edgeOff) / sizeof(int2) : 0);
    if (cap > E) cap = E;

    // zero counter + aggr (memset nodes are graph-capturable)
    hipMemsetAsync(ws, 0, edgeOff, stream);

    int fblocks = (E + FILT_CHUNK - 1) / FILT_CHUNK;
    filter_edges<<<fblocks, 256, 0, stream>>>(senders, receivers, E, n_agents,
                                              cap, counter, edges);

    edge_mlp<<<2048, 256, 0, stream>>>(x, edges, counter, cap, aggr,
                                       Wm1, bm1, Wm2, bm2, Wm3, bm3);

    node_update<<<(n_agents + NTE - 1) / NTE, 256, 0, stream>>>(
        x, actions, aggr, n_agents,
        Wa1, ba1, Wa2, ba2, Wa3, ba3,
        Wu1, bu1, Wu2, bu2, Wu3, bu3,
        Wact, bact, Wh1, bh1, Wh2, bh2, Wq, bq,
        (float*)d_out);
}